// Round 1
// baseline (318.576 us; speedup 1.0000x reference)
//
#include <hip/hip_runtime.h>

// Problem constants
#define L_SLOTS 50
#define B_SZ 1024
#define D_SZ 512
#define HDK 2048   // H*DK

// LDS row stride (pad 64 -> 68 floats keeps 16B alignment, kills write conflicts)
#define TS 68

// ---------------------------------------------------------------------------
// 64x64 tile fp32 GEMM, BK=16, 256 threads, 4x4 register micro-tile.
// C[M,N] = A[M,K] @ B[K,N]  (+bias per column when !ATOMIC)
// ATOMIC variant accumulates via atomicAdd (split-K over blockIdx.z).
// ---------------------------------------------------------------------------
template <bool ATOMIC>
__global__ __launch_bounds__(256) void gemm64(const float* __restrict__ A,
                                              const float* __restrict__ Bm,
                                              float* __restrict__ C,
                                              const float* __restrict__ bias,
                                              int M, int N, int K, int kChunk) {
    __shared__ float As[16 * TS];
    __shared__ float Bs[16 * TS];

    const int tid  = threadIdx.x;
    const int col0 = blockIdx.x * 64;
    const int row0 = blockIdx.y * 64;
    const int k0   = blockIdx.z * kChunk;
    const int k1   = k0 + kChunk;

    // global->LDS staging assignments
    const int aM = tid >> 2;          // 0..63 : row within A tile
    const int aQ = (tid & 3) << 2;    // 0,4,8,12 : k-quad
    const int bK = tid >> 4;          // 0..15 : k row within B tile
    const int bN = (tid & 15) << 2;   // 0..60 : col quad

    // compute assignments: 4 consecutive rows/cols per thread
    const int ty = tid >> 4;          // 0..15
    const int tx = tid & 15;          // 0..15

    float acc[4][4] = {};

    for (int kb = k0; kb < k1; kb += 16) {
        float4 va = *(const float4*)(A + (size_t)(row0 + aM) * K + kb + aQ);
        float4 vb = *(const float4*)(Bm + (size_t)(kb + bK) * N + col0 + bN);
        __syncthreads();   // previous iteration's LDS reads done
        As[(aQ + 0) * TS + aM] = va.x;
        As[(aQ + 1) * TS + aM] = va.y;
        As[(aQ + 2) * TS + aM] = va.z;
        As[(aQ + 3) * TS + aM] = va.w;
        *(float4*)(Bs + bK * TS + bN) = vb;
        __syncthreads();
#pragma unroll
        for (int kk = 0; kk < 16; ++kk) {
            float4 a4 = *(const float4*)(As + kk * TS + (ty << 2));
            float4 b4 = *(const float4*)(Bs + kk * TS + (tx << 2));
            float av[4] = {a4.x, a4.y, a4.z, a4.w};
            float bw[4] = {b4.x, b4.y, b4.z, b4.w};
#pragma unroll
            for (int i = 0; i < 4; ++i)
#pragma unroll
                for (int j = 0; j < 4; ++j) acc[i][j] += av[i] * bw[j];
        }
    }

    const int r0 = row0 + (ty << 2);
    const int c0 = col0 + (tx << 2);
    if (ATOMIC) {
#pragma unroll
        for (int i = 0; i < 4; ++i)
#pragma unroll
            for (int j = 0; j < 4; ++j)
                atomicAdd(&C[(size_t)(r0 + i) * N + c0 + j], acc[i][j]);
    } else {
        float4 bb = bias ? *(const float4*)(bias + c0) : make_float4(0, 0, 0, 0);
#pragma unroll
        for (int i = 0; i < 4; ++i) {
            float4 v;
            v.x = acc[i][0] + bb.x;
            v.y = acc[i][1] + bb.y;
            v.z = acc[i][2] + bb.z;
            v.w = acc[i][3] + bb.w;
            *(float4*)(C + (size_t)(r0 + i) * N + c0) = v;
        }
    }
}

// b2[o] = bo[o] + sum_j bv[j] * wo[j*512 + o]   (b2 pre-zeroed)
// 8192 threads: o = g & 511, j-chunk r = g >> 9 (16 chunks of 128)
__global__ __launch_bounds__(256) void bias_fold_kernel(const float* __restrict__ bv,
                                                        const float* __restrict__ wo,
                                                        const float* __restrict__ bo,
                                                        float* __restrict__ b2) {
    int g = blockIdx.x * 256 + threadIdx.x;
    int o = g & 511;
    int r = g >> 9;
    float s = 0.f;
    int j0 = r * 128;
#pragma unroll 4
    for (int j = j0; j < j0 + 128; ++j) s += bv[j] * wo[j * 512 + o];
    if (r == 0) s += bo[o];
    atomicAdd(&b2[o], s);
}

// out[l,b,d] = momery[l,b,d] + 3*w * temp[b,d]     (float4 granularity)
__global__ __launch_bounds__(256) void bcast_add_kernel(const float* __restrict__ mem,
                                                        const float* __restrict__ temp,
                                                        const float* __restrict__ wp,
                                                        float* __restrict__ out) {
    int idx = blockIdx.x * 256 + threadIdx.x;          // float4 index, < 6553600
    const float4 mv = ((const float4*)mem)[idx];
    int bd = idx & ((B_SZ * D_SZ / 4) - 1);            // % 131072 (pow2)
    const float4 tv = ((const float4*)temp)[bd];
    float s = 3.0f * wp[0];
    float4 o;
    o.x = mv.x + s * tv.x;
    o.y = mv.y + s * tv.y;
    o.z = mv.z + s * tv.z;
    o.w = mv.w + s * tv.w;
    ((float4*)out)[idx] = o;
}

extern "C" void kernel_launch(void* const* d_in, const int* in_sizes, int n_in,
                              void* d_out, int out_size, void* d_ws, size_t ws_size,
                              hipStream_t stream) {
    const float* momery = (const float*)d_in[0];   // [50,1024,512]
    const float* hid    = (const float*)d_in[1];   // [1024,512]
    const float* w      = (const float*)d_in[4];   // scalar
    const float* wv     = (const float*)d_in[13];  // [512,2048]
    const float* bv     = (const float*)d_in[14];  // [2048]
    const float* wo     = (const float*)d_in[15];  // [2048,512]
    const float* bo     = (const float*)d_in[16];  // [512]
    float* out = (float*)d_out;

    float* W    = (float*)d_ws;            // 512*512
    float* temp = W + 512 * 512;           // 1024*512
    float* b2   = temp + 1024 * 512;       // 512

    hipMemsetAsync(W, 0, 512 * 512 * sizeof(float), stream);
    hipMemsetAsync(b2, 0, 512 * sizeof(float), stream);

    // b2 = bv @ wo + bo
    bias_fold_kernel<<<32, 256, 0, stream>>>(bv, wo, bo, b2);

    // W = wv @ wo   (M=512, N=512, K=2048; split-K=4, atomic accumulate)
    gemm64<true><<<dim3(8, 8, 4), 256, 0, stream>>>(wv, wo, W, nullptr, 512, 512, 2048, 512);

    // temp = hid @ W + b2   (M=1024, N=512, K=512)
    gemm64<false><<<dim3(8, 16, 1), 256, 0, stream>>>(hid, W, temp, b2, 1024, 512, 512, 512);

    // out = momery + 3*w*temp   (26,214,400 floats = 25600 blocks * 256 * float4)
    bcast_add_kernel<<<25600, 256, 0, stream>>>(momery, temp, w, out);
}

// Round 2
// 288.643 us; speedup vs baseline: 1.1037x; 1.1037x over previous
//
#include <hip/hip_runtime.h>

#define B_SZ 1024
#define D_SZ 512
#define LDSP 68   // padded LDS row stride (floats); 68*4=272B keeps 16B alignment

// ---------------------------------------------------------------------------
// 64x64 tile fp32 GEMM, BK=32, 256 threads, 4x4 micro-tile, register prefetch.
// Atomic split-K accumulate into pre-zeroed C. Compile-time K / kChunk.
// ---------------------------------------------------------------------------
template <int K, int KCHUNK>
__device__ __forceinline__ void gemm_body(const float* __restrict__ A,
                                          const float* __restrict__ B,
                                          float* __restrict__ C, int N,
                                          int row0, int col0, int zk) {
    __shared__ float As[32 * LDSP];
    __shared__ float Bs[32 * LDSP];

    const int tid = threadIdx.x;
    const int k0  = zk * KCHUNK;
    constexpr int NT = KCHUNK / 32;

    // A staging: float4 #1 at (row=tid>>3, k=(tid&7)*4), #2 at row+32
    const int aR = tid >> 3;          // 0..31
    const int aK = (tid & 7) << 2;    // 0,4,..28
    // B staging: float4 #1 at (k=tid>>4, col=(tid&15)*4), #2 at k+16
    const int bK = tid >> 4;          // 0..15
    const int bC = (tid & 15) << 2;   // 0..60

    const int ty = (tid >> 4) << 2;   // acc row base 0..60
    const int tx = (tid & 15) << 2;   // acc col base 0..60

    const float* pa0 = A + (size_t)(row0 + aR) * K + k0 + aK;
    const float* pa1 = pa0 + (size_t)32 * K;
    const float* pb0 = B + (size_t)(k0 + bK) * N + col0 + bC;
    const float* pb1 = pb0 + (size_t)16 * N;

    float4 a0 = *(const float4*)pa0;
    float4 a1 = *(const float4*)pa1;
    float4 b0 = *(const float4*)pb0;
    float4 b1 = *(const float4*)pb1;

    float acc[4][4] = {};

    for (int t = 0; t < NT; ++t) {
        __syncthreads();
        As[(aK + 0) * LDSP + aR] = a0.x;
        As[(aK + 1) * LDSP + aR] = a0.y;
        As[(aK + 2) * LDSP + aR] = a0.z;
        As[(aK + 3) * LDSP + aR] = a0.w;
        As[(aK + 0) * LDSP + aR + 32] = a1.x;
        As[(aK + 1) * LDSP + aR + 32] = a1.y;
        As[(aK + 2) * LDSP + aR + 32] = a1.z;
        As[(aK + 3) * LDSP + aR + 32] = a1.w;
        *(float4*)(Bs + bK * LDSP + bC) = b0;
        *(float4*)(Bs + (bK + 16) * LDSP + bC) = b1;
        if (t + 1 < NT) {           // issue next tile's loads before compute
            pa0 += 32; pa1 += 32;
            pb0 += (size_t)32 * N; pb1 += (size_t)32 * N;
            a0 = *(const float4*)pa0;
            a1 = *(const float4*)pa1;
            b0 = *(const float4*)pb0;
            b1 = *(const float4*)pb1;
        }
        __syncthreads();
#pragma unroll
        for (int kk = 0; kk < 32; ++kk) {
            float4 av = *(const float4*)(As + kk * LDSP + ty);
            float4 bv = *(const float4*)(Bs + kk * LDSP + tx);
            float ar[4] = {av.x, av.y, av.z, av.w};
            float br[4] = {bv.x, bv.y, bv.z, bv.w};
#pragma unroll
            for (int i = 0; i < 4; ++i)
#pragma unroll
                for (int j = 0; j < 4; ++j) acc[i][j] += ar[i] * br[j];
        }
    }

    const int r0 = row0 + ty;
    const int c0 = col0 + tx;
#pragma unroll
    for (int i = 0; i < 4; ++i)
#pragma unroll
        for (int j = 0; j < 4; ++j)
            atomicAdd(&C[(size_t)(r0 + i) * N + c0 + j], acc[i][j]);
}

// GEMM-A (W = wv @ wo, M=N=512, K=2048, split-K=4) + bias slice (z==4):
// b2 += bv @ wo (+bo), 64 bias blocks, 64 j-iters per thread.
__global__ __launch_bounds__(256) void gemmA_bias(const float* __restrict__ wv,
                                                  const float* __restrict__ wo,
                                                  const float* __restrict__ bv,
                                                  const float* __restrict__ bo,
                                                  float* __restrict__ W,
                                                  float* __restrict__ b2) {
    if (blockIdx.z == 4) {
        int bid = blockIdx.y * 8 + blockIdx.x;         // 0..63
        int g = bid * 256 + threadIdx.x;               // 0..16383
        int o = g & 511;
        int r = g >> 9;                                // 0..31
        float s = 0.f;
        int j0 = r * 64;
#pragma unroll 8
        for (int j = j0; j < j0 + 64; ++j) s += bv[j] * wo[j * 512 + o];
        if (r == 0) s += bo[o];
        atomicAdd(&b2[o], s);
        return;
    }
    gemm_body<2048, 512>(wv, wo, W, 512, blockIdx.y * 64, blockIdx.x * 64,
                         blockIdx.z);
}

// GEMM-B: temp += hid @ W   (M=1024, N=512, K=512, split-K=2; bias in bcast)
__global__ __launch_bounds__(256) void gemmB(const float* __restrict__ hid,
                                             const float* __restrict__ W,
                                             float* __restrict__ temp) {
    gemm_body<512, 256>(hid, W, temp, 512, blockIdx.y * 64, blockIdx.x * 64,
                        blockIdx.z);
}

// out[l,b,d] = momery[l,b,d] + 3*w * (temp[b,d] + b2[d])
__global__ __launch_bounds__(256) void bcast_add_kernel(const float* __restrict__ mem,
                                                        const float* __restrict__ temp,
                                                        const float* __restrict__ b2,
                                                        const float* __restrict__ wp,
                                                        float* __restrict__ out) {
    int idx = blockIdx.x * 256 + threadIdx.x;          // float4 index, < 6553600
    const float4 mv = ((const float4*)mem)[idx];
    int bd = idx & ((B_SZ * D_SZ / 4) - 1);            // fast % 131072
    const float4 tv = ((const float4*)temp)[bd];
    const float4 bb = ((const float4*)b2)[bd & 127];   // d-quad within row
    float s = 3.0f * wp[0];
    float4 o;
    o.x = mv.x + s * (tv.x + bb.x);
    o.y = mv.y + s * (tv.y + bb.y);
    o.z = mv.z + s * (tv.z + bb.z);
    o.w = mv.w + s * (tv.w + bb.w);
    ((float4*)out)[idx] = o;
}

extern "C" void kernel_launch(void* const* d_in, const int* in_sizes, int n_in,
                              void* d_out, int out_size, void* d_ws, size_t ws_size,
                              hipStream_t stream) {
    const float* momery = (const float*)d_in[0];   // [50,1024,512]
    const float* hid    = (const float*)d_in[1];   // [1024,512]
    const float* w      = (const float*)d_in[4];   // scalar
    const float* wv     = (const float*)d_in[13];  // [512,2048]
    const float* bv     = (const float*)d_in[14];  // [2048]
    const float* wo     = (const float*)d_in[15];  // [2048,512]
    const float* bo     = (const float*)d_in[16];  // [512]
    float* out = (float*)d_out;

    // ws layout (contiguous so ONE memset zeroes all accumulators):
    float* W    = (float*)d_ws;            // 512*512          = 262144
    float* b2   = W + 512 * 512;           // 512              (16B-aligned)
    float* temp = b2 + 512;                // 1024*512         (16B-aligned)
    size_t zbytes = (size_t)(512 * 512 + 512 + 1024 * 512) * sizeof(float);

    hipMemsetAsync(d_ws, 0, zbytes, stream);

    // W = wv@wo (split-K=4) and b2 = bv@wo + bo (z==4 slice), one launch
    gemmA_bias<<<dim3(8, 8, 5), 256, 0, stream>>>(wv, wo, bv, bo, W, b2);

    // temp = hid @ W (split-K=2)
    gemmB<<<dim3(8, 16, 2), 256, 0, stream>>>(hid, W, temp);

    // out = momery + 3w*(temp + b2)
    bcast_add_kernel<<<25600, 256, 0, stream>>>(momery, temp, b2, w, out);
}

// Round 3
// 257.399 us; speedup vs baseline: 1.2377x; 1.1214x over previous
//
#include <hip/hip_runtime.h>

#define B_SZ 1024
#define D_SZ 512
#define LDSP 68   // padded LDS row stride (floats); keeps float4 alignment

__device__ __forceinline__ float4 f4add(float4 a, float4 b) {
    return make_float4(a.x + b.x, a.y + b.y, a.z + b.z, a.w + b.w);
}

// ---------------------------------------------------------------------------
// GEMM-A: Wp[z] = wv[:, z*512:(z+1)*512-chunk] @ wo  (split-K=4, non-atomic
// partial stores). 64x64 tile, BK=32, 256 threads, 4x4 micro-tile, register
// prefetch. z==0 blocks also emit bias partials b2p[32][512].
// ---------------------------------------------------------------------------
__global__ __launch_bounds__(256) void gemmA(const float* __restrict__ wv,
                                             const float* __restrict__ wo,
                                             const float* __restrict__ bv,
                                             const float* __restrict__ bo,
                                             float* __restrict__ Wp,
                                             float* __restrict__ b2p) {
    __shared__ float As[32 * LDSP];
    __shared__ float Bs[32 * LDSP];

    const int tid  = threadIdx.x;
    const int col0 = blockIdx.x * 64;
    const int row0 = blockIdx.y * 64;
    const int z    = blockIdx.z;          // 0..3
    const int k0   = z * 512;
    constexpr int K = 2048, N = 512, NT = 16;

    const int aR = tid >> 3;              // 0..31
    const int aK = (tid & 7) << 2;        // 0..28
    const int bK = tid >> 4;              // 0..15
    const int bC = (tid & 15) << 2;       // 0..60
    const int ty = (tid >> 4) << 2;       // 0..60
    const int tx = (tid & 15) << 2;       // 0..60

    const float* pa0 = wv + (size_t)(row0 + aR) * K + k0 + aK;
    const float* pa1 = pa0 + (size_t)32 * K;
    const float* pb0 = wo + (size_t)(k0 + bK) * N + col0 + bC;
    const float* pb1 = pb0 + (size_t)16 * N;

    float4 a0 = *(const float4*)pa0;
    float4 a1 = *(const float4*)pa1;
    float4 b0 = *(const float4*)pb0;
    float4 b1 = *(const float4*)pb1;

    float acc[4][4] = {};

    for (int t = 0; t < NT; ++t) {
        __syncthreads();
        As[(aK + 0) * LDSP + aR] = a0.x;
        As[(aK + 1) * LDSP + aR] = a0.y;
        As[(aK + 2) * LDSP + aR] = a0.z;
        As[(aK + 3) * LDSP + aR] = a0.w;
        As[(aK + 0) * LDSP + aR + 32] = a1.x;
        As[(aK + 1) * LDSP + aR + 32] = a1.y;
        As[(aK + 2) * LDSP + aR + 32] = a1.z;
        As[(aK + 3) * LDSP + aR + 32] = a1.w;
        *(float4*)(Bs + bK * LDSP + bC) = b0;
        *(float4*)(Bs + (bK + 16) * LDSP + bC) = b1;
        if (t + 1 < NT) {
            pa0 += 32; pa1 += 32;
            pb0 += (size_t)32 * N; pb1 += (size_t)32 * N;
            a0 = *(const float4*)pa0;
            a1 = *(const float4*)pa1;
            b0 = *(const float4*)pb0;
            b1 = *(const float4*)pb1;
        }
        __syncthreads();
#pragma unroll
        for (int kk = 0; kk < 32; ++kk) {
            float4 av = *(const float4*)(As + kk * LDSP + ty);
            float4 bv4 = *(const float4*)(Bs + kk * LDSP + tx);
            float ar[4] = {av.x, av.y, av.z, av.w};
            float br[4] = {bv4.x, bv4.y, bv4.z, bv4.w};
#pragma unroll
            for (int i = 0; i < 4; ++i)
#pragma unroll
                for (int j = 0; j < 4; ++j) acc[i][j] += ar[i] * br[j];
        }
    }

    float* C = Wp + (size_t)z * 262144;   // 512*512 partial
    const int r0 = row0 + ty, c0 = col0 + tx;
#pragma unroll
    for (int i = 0; i < 4; ++i)
        *(float4*)(C + (size_t)(r0 + i) * N + c0) =
            make_float4(acc[i][0], acc[i][1], acc[i][2], acc[i][3]);

    // bias partials: 64 z==0 blocks x 256 threads = 32 chunks x 512 outputs
    if (z == 0) {
        int bid = blockIdx.y * 8 + blockIdx.x;   // 0..63
        int g = bid * 256 + tid;                 // 0..16383
        int o = g & 511;
        int r = g >> 9;                          // 0..31
        float s = (r == 0) ? bo[o] : 0.f;
        int j0 = r * 64;
#pragma unroll 8
        for (int j = j0; j < j0 + 64; ++j) s += bv[j] * wo[j * 512 + o];
        b2p[r * 512 + o] = s;
    }
}

// ---------------------------------------------------------------------------
// GEMM-B: tp[z] = hid @ (W0+W1+W2+W3) split-K=2, non-atomic. B-tile staged as
// the sum of the 4 Wp partials. z==0 adds bias (reduced from b2p via LDS).
// ---------------------------------------------------------------------------
__global__ __launch_bounds__(256) void gemmB(const float* __restrict__ hid,
                                             const float* __restrict__ Wp,
                                             const float* __restrict__ b2p,
                                             float* __restrict__ t0,
                                             float* __restrict__ t1) {
    __shared__ float As[32 * LDSP];
    __shared__ float Bs[32 * LDSP];

    const int tid  = threadIdx.x;
    const int col0 = blockIdx.x * 64;
    const int row0 = blockIdx.y * 64;
    const int z    = blockIdx.z;          // 0..1
    const int k0   = z * 256;
    constexpr int K = 512, N = 512, NT = 8;

    const int aR = tid >> 3;
    const int aK = (tid & 7) << 2;
    const int bK = tid >> 4;
    const int bC = (tid & 15) << 2;
    const int ty = (tid >> 4) << 2;
    const int tx = (tid & 15) << 2;

    const float* pa0 = hid + (size_t)(row0 + aR) * K + k0 + aK;
    const float* pa1 = pa0 + (size_t)32 * K;
    const float* pb0 = Wp + (size_t)(k0 + bK) * N + col0 + bC;
    const float* pb1 = pb0 + (size_t)16 * N;

    float4 a0 = *(const float4*)pa0;
    float4 a1 = *(const float4*)pa1;
    float4 vb0[4], vb1[4];
#pragma unroll
    for (int p = 0; p < 4; ++p) {
        vb0[p] = *(const float4*)(pb0 + (size_t)p * 262144);
        vb1[p] = *(const float4*)(pb1 + (size_t)p * 262144);
    }

    float acc[4][4] = {};

    for (int t = 0; t < NT; ++t) {
        float4 sb0 = f4add(f4add(vb0[0], vb0[1]), f4add(vb0[2], vb0[3]));
        float4 sb1 = f4add(f4add(vb1[0], vb1[1]), f4add(vb1[2], vb1[3]));
        __syncthreads();
        As[(aK + 0) * LDSP + aR] = a0.x;
        As[(aK + 1) * LDSP + aR] = a0.y;
        As[(aK + 2) * LDSP + aR] = a0.z;
        As[(aK + 3) * LDSP + aR] = a0.w;
        As[(aK + 0) * LDSP + aR + 32] = a1.x;
        As[(aK + 1) * LDSP + aR + 32] = a1.y;
        As[(aK + 2) * LDSP + aR + 32] = a1.z;
        As[(aK + 3) * LDSP + aR + 32] = a1.w;
        *(float4*)(Bs + bK * LDSP + bC) = sb0;
        *(float4*)(Bs + (bK + 16) * LDSP + bC) = sb1;
        if (t + 1 < NT) {
            pa0 += 32; pa1 += 32;
            pb0 += (size_t)32 * N; pb1 += (size_t)32 * N;
            a0 = *(const float4*)pa0;
            a1 = *(const float4*)pa1;
#pragma unroll
            for (int p = 0; p < 4; ++p) {
                vb0[p] = *(const float4*)(pb0 + (size_t)p * 262144);
                vb1[p] = *(const float4*)(pb1 + (size_t)p * 262144);
            }
        }
        __syncthreads();
#pragma unroll
        for (int kk = 0; kk < 32; ++kk) {
            float4 av = *(const float4*)(As + kk * LDSP + ty);
            float4 bv4 = *(const float4*)(Bs + kk * LDSP + tx);
            float ar[4] = {av.x, av.y, av.z, av.w};
            float br[4] = {bv4.x, bv4.y, bv4.z, bv4.w};
#pragma unroll
            for (int i = 0; i < 4; ++i)
#pragma unroll
                for (int j = 0; j < 4; ++j) acc[i][j] += ar[i] * br[j];
        }
    }

    // z==0 blocks fold the bias for their 64 columns (reduce b2p in LDS)
    __syncthreads();
    if (z == 0 && tid < 64) {
        float s = 0.f;
#pragma unroll 8
        for (int r = 0; r < 32; ++r) s += b2p[r * 512 + col0 + tid];
        Bs[tid] = s;
    }
    __syncthreads();
    float4 bb = make_float4(0, 0, 0, 0);
    if (z == 0) bb = *(const float4*)(Bs + tx);

    float* C = z ? t1 : t0;
    const int r0 = row0 + ty, c0 = col0 + tx;
#pragma unroll
    for (int i = 0; i < 4; ++i)
        *(float4*)(C + (size_t)(r0 + i) * N + c0) =
            make_float4(acc[i][0] + bb.x, acc[i][1] + bb.y,
                        acc[i][2] + bb.z, acc[i][3] + bb.w);
}

// out[l,b,d] = momery[l,b,d] + 3*w * (t0[b,d] + t1[b,d])
__global__ __launch_bounds__(256) void bcast_add_kernel(const float* __restrict__ mem,
                                                        const float* __restrict__ t0,
                                                        const float* __restrict__ t1,
                                                        const float* __restrict__ wp,
                                                        float* __restrict__ out) {
    int idx = blockIdx.x * 256 + threadIdx.x;          // float4 index
    const float4 mv = ((const float4*)mem)[idx];
    int bd = idx & ((B_SZ * D_SZ / 4) - 1);
    const float4 a = ((const float4*)t0)[bd];
    const float4 b = ((const float4*)t1)[bd];
    float s = 3.0f * wp[0];
    float4 o;
    o.x = mv.x + s * (a.x + b.x);
    o.y = mv.y + s * (a.y + b.y);
    o.z = mv.z + s * (a.z + b.z);
    o.w = mv.w + s * (a.w + b.w);
    ((float4*)out)[idx] = o;
}

extern "C" void kernel_launch(void* const* d_in, const int* in_sizes, int n_in,
                              void* d_out, int out_size, void* d_ws, size_t ws_size,
                              hipStream_t stream) {
    const float* momery = (const float*)d_in[0];   // [50,1024,512]
    const float* hid    = (const float*)d_in[1];   // [1024,512]
    const float* w      = (const float*)d_in[4];   // scalar
    const float* wv     = (const float*)d_in[13];  // [512,2048]
    const float* bv     = (const float*)d_in[14];  // [2048]
    const float* wo     = (const float*)d_in[15];  // [2048,512]
    const float* bo     = (const float*)d_in[16];  // [512]
    float* out = (float*)d_out;

    float* Wp  = (float*)d_ws;          // 4 x 512*512 = 1048576 floats
    float* b2p = Wp + 4 * 262144;       // 32*512 = 16384
    float* t0  = b2p + 16384;           // 1024*512
    float* t1  = t0 + 524288;           // 1024*512

    // Wp[z] = wv@wo split-K partials; b2p = chunked bv@wo + bo
    gemmA<<<dim3(8, 8, 4), 256, 0, stream>>>(wv, wo, bv, bo, Wp, b2p);

    // t0/t1 = hid @ sum(Wp) split-K partials; bias folded into t0
    gemmB<<<dim3(8, 16, 2), 256, 0, stream>>>(hid, Wp, b2p, t0, t1);

    // out = momery + 3w*(t0+t1)
    bcast_add_kernel<<<25600, 256, 0, stream>>>(momery, t0, t1, w, out);
}

// Round 4
// 251.971 us; speedup vs baseline: 1.2643x; 1.0215x over previous
//
#include <hip/hip_runtime.h>
#include <hip/hip_bf16.h>

#define B_SZ 1024
#define D_SZ 512

typedef short short8 __attribute__((ext_vector_type(8)));
typedef float f4 __attribute__((ext_vector_type(4)));

__device__ __forceinline__ short f2bfs(float f) {
    __hip_bfloat16 h = __float2bfloat16(f);
    return __builtin_bit_cast(short, h);
}

// ---------------------------------------------------------------------------
// GEMM-A: Wp[z] = wv[:, z*512 .. +512] @ wo   (split-K=4, fp32 partial stores)
// 64x64 tile, BK=32, 256 threads = 4 waves in 2x2 quadrants, MFMA bf16,
// fragments loaded DIRECTLY from L2-resident globals (no LDS, no barriers).
// z==0 blocks also emit bias partials b2p[32][512] (fp32 tail, as R3).
// ---------------------------------------------------------------------------
__global__ __launch_bounds__(256) void gemmA(const float* __restrict__ wv,
                                             const float* __restrict__ wo,
                                             const float* __restrict__ bv,
                                             const float* __restrict__ bo,
                                             float* __restrict__ Wp,
                                             float* __restrict__ b2p) {
    constexpr int K = 2048, N = 512, NT = 16;
    const int tid  = threadIdx.x;
    const int col0 = blockIdx.x * 64;
    const int row0 = blockIdx.y * 64;
    const int z    = blockIdx.z;
    const int k0   = z * 512;

    const int lane = tid & 63;
    const int wave = tid >> 6;
    const int mq = wave >> 1, nq = wave & 1;
    const int ln = lane & 15, q = lane >> 4;

    const int rowA0 = row0 + mq * 32 + ln;      // a-frag rows
    const int rowA1 = rowA0 + 16;
    const int colB0 = col0 + nq * 32 + ln;      // b-frag cols
    const int colB1 = colB0 + 16;

    // pointers at k = k0 + q*8 (each lane reads 8 contiguous k for A,
    // 8 strided rows for B)
    const float* pa0 = wv + (size_t)rowA0 * K + k0 + q * 8;
    const float* pa1 = wv + (size_t)rowA1 * K + k0 + q * 8;
    const float* pb  = wo + (size_t)(k0 + q * 8) * N;

    float4 a00 = *(const float4*)pa0, a01 = *(const float4*)(pa0 + 4);
    float4 a10 = *(const float4*)pa1, a11 = *(const float4*)(pa1 + 4);
    float b0r[8], b1r[8];
#pragma unroll
    for (int j = 0; j < 8; ++j) {
        b0r[j] = pb[(size_t)j * N + colB0];
        b1r[j] = pb[(size_t)j * N + colB1];
    }

    f4 acc00 = {0,0,0,0}, acc01 = {0,0,0,0}, acc10 = {0,0,0,0}, acc11 = {0,0,0,0};

    for (int t = 0; t < NT; ++t) {
        short8 af0, af1, bf0, bf1;
        af0[0]=f2bfs(a00.x); af0[1]=f2bfs(a00.y); af0[2]=f2bfs(a00.z); af0[3]=f2bfs(a00.w);
        af0[4]=f2bfs(a01.x); af0[5]=f2bfs(a01.y); af0[6]=f2bfs(a01.z); af0[7]=f2bfs(a01.w);
        af1[0]=f2bfs(a10.x); af1[1]=f2bfs(a10.y); af1[2]=f2bfs(a10.z); af1[3]=f2bfs(a10.w);
        af1[4]=f2bfs(a11.x); af1[5]=f2bfs(a11.y); af1[6]=f2bfs(a11.z); af1[7]=f2bfs(a11.w);
#pragma unroll
        for (int j = 0; j < 8; ++j) { bf0[j] = f2bfs(b0r[j]); bf1[j] = f2bfs(b1r[j]); }

        if (t + 1 < NT) {      // prefetch next K-tile while MFMAs run
            pa0 += 32; pa1 += 32; pb += (size_t)32 * N;
            a00 = *(const float4*)pa0; a01 = *(const float4*)(pa0 + 4);
            a10 = *(const float4*)pa1; a11 = *(const float4*)(pa1 + 4);
#pragma unroll
            for (int j = 0; j < 8; ++j) {
                b0r[j] = pb[(size_t)j * N + colB0];
                b1r[j] = pb[(size_t)j * N + colB1];
            }
        }
        acc00 = __builtin_amdgcn_mfma_f32_16x16x32_bf16(af0, bf0, acc00, 0, 0, 0);
        acc01 = __builtin_amdgcn_mfma_f32_16x16x32_bf16(af0, bf1, acc01, 0, 0, 0);
        acc10 = __builtin_amdgcn_mfma_f32_16x16x32_bf16(af1, bf0, acc10, 0, 0, 0);
        acc11 = __builtin_amdgcn_mfma_f32_16x16x32_bf16(af1, bf1, acc11, 0, 0, 0);
    }

    // D layout: row = quad*4 + reg, col = lane&15
    float* C = Wp + (size_t)z * 262144;
    const int r0 = row0 + mq * 32 + q * 4;
    const int c0 = col0 + nq * 32 + ln;
#pragma unroll
    for (int r = 0; r < 4; ++r) {
        C[(size_t)(r0 + r) * N + c0]           = acc00[r];
        C[(size_t)(r0 + r) * N + c0 + 16]      = acc01[r];
        C[(size_t)(r0 + 16 + r) * N + c0]      = acc10[r];
        C[(size_t)(r0 + 16 + r) * N + c0 + 16] = acc11[r];
    }

    // bias partials: 64 z==0 blocks x 256 threads = 32 chunks x 512 outputs
    if (z == 0) {
        int bid = blockIdx.y * 8 + blockIdx.x;   // 0..63
        int g = bid * 256 + tid;                 // 0..16383
        int o = g & 511;
        int r = g >> 9;                          // 0..31
        float s = (r == 0) ? bo[o] : 0.f;
        int j0 = r * 64;
#pragma unroll 8
        for (int j = j0; j < j0 + 64; ++j) s += bv[j] * wo[j * 512 + o];
        b2p[r * 512 + o] = s;
    }
}

// ---------------------------------------------------------------------------
// GEMM-B: t{0,1} = hid @ (W0+W1+W2+W3) split-K=2, MFMA bf16, no-LDS main
// loop; the 4 Wp partials are summed in-flight during the B-fragment load.
// z==0 adds bias (b2p reduced via small LDS array).
// ---------------------------------------------------------------------------
__global__ __launch_bounds__(256) void gemmB(const float* __restrict__ hid,
                                             const float* __restrict__ Wp,
                                             const float* __restrict__ b2p,
                                             float* __restrict__ t0,
                                             float* __restrict__ t1) {
    constexpr int K = 512, N = 512, NT = 8;
    __shared__ float biasS[64];

    const int tid  = threadIdx.x;
    const int col0 = blockIdx.x * 64;
    const int row0 = blockIdx.y * 64;
    const int z    = blockIdx.z;          // 0..1
    const int k0   = z * 256;

    const int lane = tid & 63;
    const int wave = tid >> 6;
    const int mq = wave >> 1, nq = wave & 1;
    const int ln = lane & 15, q = lane >> 4;

    const int rowA0 = row0 + mq * 32 + ln;
    const int rowA1 = rowA0 + 16;
    const int colB0 = col0 + nq * 32 + ln;
    const int colB1 = colB0 + 16;

    const float* pa0 = hid + (size_t)rowA0 * K + k0 + q * 8;
    const float* pa1 = hid + (size_t)rowA1 * K + k0 + q * 8;
    const float* pb  = Wp + (size_t)(k0 + q * 8) * N;

    float4 a00 = *(const float4*)pa0, a01 = *(const float4*)(pa0 + 4);
    float4 a10 = *(const float4*)pa1, a11 = *(const float4*)(pa1 + 4);
    float b0r[8], b1r[8];
#pragma unroll
    for (int j = 0; j < 8; ++j) {
        size_t off = (size_t)j * N;
        b0r[j] = pb[off + colB0]           + pb[off + colB0 + 262144]
               + pb[off + colB0 + 524288]  + pb[off + colB0 + 786432];
        b1r[j] = pb[off + colB1]           + pb[off + colB1 + 262144]
               + pb[off + colB1 + 524288]  + pb[off + colB1 + 786432];
    }

    f4 acc00 = {0,0,0,0}, acc01 = {0,0,0,0}, acc10 = {0,0,0,0}, acc11 = {0,0,0,0};

    for (int t = 0; t < NT; ++t) {
        short8 af0, af1, bf0, bf1;
        af0[0]=f2bfs(a00.x); af0[1]=f2bfs(a00.y); af0[2]=f2bfs(a00.z); af0[3]=f2bfs(a00.w);
        af0[4]=f2bfs(a01.x); af0[5]=f2bfs(a01.y); af0[6]=f2bfs(a01.z); af0[7]=f2bfs(a01.w);
        af1[0]=f2bfs(a10.x); af1[1]=f2bfs(a10.y); af1[2]=f2bfs(a10.z); af1[3]=f2bfs(a10.w);
        af1[4]=f2bfs(a11.x); af1[5]=f2bfs(a11.y); af1[6]=f2bfs(a11.z); af1[7]=f2bfs(a11.w);
#pragma unroll
        for (int j = 0; j < 8; ++j) { bf0[j] = f2bfs(b0r[j]); bf1[j] = f2bfs(b1r[j]); }

        if (t + 1 < NT) {
            pa0 += 32; pa1 += 32; pb += (size_t)32 * N;
            a00 = *(const float4*)pa0; a01 = *(const float4*)(pa0 + 4);
            a10 = *(const float4*)pa1; a11 = *(const float4*)(pa1 + 4);
#pragma unroll
            for (int j = 0; j < 8; ++j) {
                size_t off = (size_t)j * N;
                b0r[j] = pb[off + colB0]           + pb[off + colB0 + 262144]
                       + pb[off + colB0 + 524288]  + pb[off + colB0 + 786432];
                b1r[j] = pb[off + colB1]           + pb[off + colB1 + 262144]
                       + pb[off + colB1 + 524288]  + pb[off + colB1 + 786432];
            }
        }
        acc00 = __builtin_amdgcn_mfma_f32_16x16x32_bf16(af0, bf0, acc00, 0, 0, 0);
        acc01 = __builtin_amdgcn_mfma_f32_16x16x32_bf16(af0, bf1, acc01, 0, 0, 0);
        acc10 = __builtin_amdgcn_mfma_f32_16x16x32_bf16(af1, bf0, acc10, 0, 0, 0);
        acc11 = __builtin_amdgcn_mfma_f32_16x16x32_bf16(af1, bf1, acc11, 0, 0, 0);
    }

    // bias reduce for z==0 (threads 0..63 cover this block's 64 columns)
    if (z == 0 && tid < 64) {
        float s = 0.f;
#pragma unroll 8
        for (int r = 0; r < 32; ++r) s += b2p[r * 512 + col0 + tid];
        biasS[tid] = s;
    }
    __syncthreads();
    float bj0 = 0.f, bj1 = 0.f;
    if (z == 0) { bj0 = biasS[nq * 32 + ln]; bj1 = biasS[nq * 32 + 16 + ln]; }

    float* C = z ? t1 : t0;
    const int r0 = row0 + mq * 32 + q * 4;
    const int c0 = col0 + nq * 32 + ln;
#pragma unroll
    for (int r = 0; r < 4; ++r) {
        C[(size_t)(r0 + r) * N + c0]           = acc00[r] + bj0;
        C[(size_t)(r0 + r) * N + c0 + 16]      = acc01[r] + bj1;
        C[(size_t)(r0 + 16 + r) * N + c0]      = acc10[r] + bj0;
        C[(size_t)(r0 + 16 + r) * N + c0 + 16] = acc11[r] + bj1;
    }
}

// out[l,b,d] = momery[l,b,d] + 3*w * (t0[b,d] + t1[b,d])
__global__ __launch_bounds__(256) void bcast_add_kernel(const float* __restrict__ mem,
                                                        const float* __restrict__ t0,
                                                        const float* __restrict__ t1,
                                                        const float* __restrict__ wp,
                                                        float* __restrict__ out) {
    int idx = blockIdx.x * 256 + threadIdx.x;          // float4 index
    const float4 mv = ((const float4*)mem)[idx];
    int bd = idx & ((B_SZ * D_SZ / 4) - 1);
    const float4 a = ((const float4*)t0)[bd];
    const float4 b = ((const float4*)t1)[bd];
    float s = 3.0f * wp[0];
    float4 o;
    o.x = mv.x + s * (a.x + b.x);
    o.y = mv.y + s * (a.y + b.y);
    o.z = mv.z + s * (a.z + b.z);
    o.w = mv.w + s * (a.w + b.w);
    ((float4*)out)[idx] = o;
}

extern "C" void kernel_launch(void* const* d_in, const int* in_sizes, int n_in,
                              void* d_out, int out_size, void* d_ws, size_t ws_size,
                              hipStream_t stream) {
    const float* momery = (const float*)d_in[0];   // [50,1024,512]
    const float* hid    = (const float*)d_in[1];   // [1024,512]
    const float* w      = (const float*)d_in[4];   // scalar
    const float* wv     = (const float*)d_in[13];  // [512,2048]
    const float* bv     = (const float*)d_in[14];  // [2048]
    const float* wo     = (const float*)d_in[15];  // [2048,512]
    const float* bo     = (const float*)d_in[16];  // [512]
    float* out = (float*)d_out;

    float* Wp  = (float*)d_ws;          // 4 x 512*512 = 1048576 floats
    float* b2p = Wp + 4 * 262144;       // 32*512 = 16384
    float* t0  = b2p + 16384;           // 1024*512
    float* t1  = t0 + 524288;           // 1024*512

    // Wp[z] = wv@wo split-K partials (MFMA); b2p = chunked bv@wo + bo
    gemmA<<<dim3(8, 8, 4), 256, 0, stream>>>(wv, wo, bv, bo, Wp, b2p);

    // t0/t1 = hid @ sum(Wp) split-K partials (MFMA); bias folded into t0
    gemmB<<<dim3(8, 16, 2), 256, 0, stream>>>(hid, Wp, b2p, t0, t1);

    // out = momery + 3w*(t0+t1)
    bcast_add_kernel<<<25600, 256, 0, stream>>>(momery, t0, t1, w, out);
}